// Round 4
// baseline (475.877 us; speedup 1.0000x reference)
//
#include <hip/hip_runtime.h>
#include <stdint.h>
#include <math.h>

typedef _Float16 f16;
typedef _Float16 f16x8 __attribute__((ext_vector_type(8)));
typedef float f32x4 __attribute__((ext_vector_type(4)));

#define KD 704
#define NPTS 8192
#define ROWB 1408  // KD * 2 bytes

typedef const unsigned __attribute__((address_space(1)))* gas_ptr;
typedef unsigned __attribute__((address_space(3)))* las_ptr;

__device__ __forceinline__ void gld16(const void* g, void* l) {
  __builtin_amdgcn_global_load_lds((gas_ptr)g, (las_ptr)l, 16, 0, 0);
}

__device__ __forceinline__ unsigned long long packkey(float v, int idx) {
  unsigned b = __float_as_uint(v);
  b ^= ((unsigned)((int)b >> 31)) | 0x80000000u;  // monotone float->uint
  return ((unsigned long long)b << 32) | (unsigned)(~idx);  // ~idx: ties -> smaller idx
}

// ---- kernel 1: column norms (x256 fold) + zero the 16K atomic slots ----
__global__ void k_norm(const float* __restrict__ A, const float* __restrict__ B,
                       float* __restrict__ invA, float* __restrict__ invB,
                       unsigned long long* __restrict__ slots) {
  __shared__ float p[256];
  const int blk = blockIdx.x;  // 0..511
  const int mat = blk >> 8;
  const float* M = mat ? B : A;
  float* inv = mat ? invB : invA;
  const int cbase = (blk & 255) << 5;
  const int c = cbase + (threadIdx.x & 31);
  const int s = threadIdx.x >> 5;  // 0..7
  float ss = 0.f;
  for (int d = s; d < KD; d += 8) {
    float x = M[(size_t)d * NPTS + c];
    ss = fmaf(x, x, ss);
  }
  p[threadIdx.x] = ss;
  if (blk < 64) slots[blk * 256 + threadIdx.x] = 0ull;  // rowbest+colbest (128 KB)
  __syncthreads();
  if (threadIdx.x < 32) {
    float t = 0.f;
    #pragma unroll
    for (int k = 0; k < 8; ++k) t += p[k * 32 + threadIdx.x];
    inv[cbase + threadIdx.x] = 256.0f / sqrtf(t);
  }
}

// ---- kernel 2: transpose (D,N)->(N,D), normalize, fp16 hi/lo split ----
__global__ void k_split(const float* __restrict__ A, const float* __restrict__ B,
                        const float* __restrict__ invA, const float* __restrict__ invB,
                        f16* __restrict__ Ahi, f16* __restrict__ Alo,
                        f16* __restrict__ Bhi, f16* __restrict__ Blo) {
  __shared__ float t[32][33];
  const int z = blockIdx.z;
  const float* M   = z ? B    : A;
  const float* inv = z ? invB : invA;
  f16* Hi = z ? Bhi : Ahi;
  f16* Lo = z ? Blo : Alo;
  const int c0 = blockIdx.x * 32, d0 = blockIdx.y * 32;
  const int tx = threadIdx.x & 31, ty = threadIdx.x >> 5;
  #pragma unroll
  for (int s = 0; s < 4; ++s)
    t[ty + s * 8][tx] = M[(size_t)(d0 + ty + s * 8) * NPTS + (c0 + tx)];
  __syncthreads();
  const int tx16 = threadIdx.x & 15, ty16 = threadIdx.x >> 4;  // 16x16
  #pragma unroll
  for (int s2 = 0; s2 < 2; ++s2) {
    const int i = c0 + ty16 + s2 * 16;
    const float iv = inv[i];
    const float v0 = t[tx16 * 2][ty16 + s2 * 16] * iv;
    const float v1 = t[tx16 * 2 + 1][ty16 + s2 * 16] * iv;
    const f16 h0 = (f16)v0, h1 = (f16)v1;
    const f16 l0 = (f16)(v0 - (float)h0), l1 = (f16)(v1 - (float)h1);
    const size_t o = (size_t)i * KD + d0 + tx16 * 2;
    Hi[o] = h0; Hi[o + 1] = h1;
    Lo[o] = l0; Lo[o + 1] = l1;
  }
}

// ---- kernel 3: 256x256-tile K_eff=2112 deep-pipelined GEMM + fused top-1 ----
// K-extension: tiles 0-10 = Ah*Bh, 11-21 = Ah*Bl, 22-32 = Al*Bh (3-product f16 split).
__global__ __launch_bounds__(512, 2)
void k_gemm_top1(const f16* __restrict__ Ah_, const f16* __restrict__ Al_,
                 const f16* __restrict__ Bh_, const f16* __restrict__ Bl_,
                 unsigned long long* __restrict__ rowbest,
                 unsigned long long* __restrict__ colbest) {
  __shared__ f16 sA[2][256][64];  // 64 KB: [dbuf][row][k], XOR-8 swizzle on 16B slots
  __shared__ f16 sB[2][256][64];  // 64 KB

  const int tid = threadIdx.x;
  const int lane = tid & 63, w = tid >> 6;
  const int wr = w >> 2, wc = w & 3;  // 2 x 4 wave grid; per-wave out 128x64

  // XCD-bijective swizzle (1024 blocks % 8 == 0)
  const int lin = blockIdx.x;
  const int swz = (lin & 7) * 128 + (lin >> 3);
  const int bi = swz >> 5, bj = swz & 31;

  const char* Ah = (const char*)Ah_;
  const char* Al = (const char*)Al_;
  const char* Bh = (const char*)Bh_;
  const char* Bl = (const char*)Bl_;
  const size_t arow = (size_t)(bi * 256) * ROWB;
  const size_t brow = (size_t)(bj * 256) * ROWB;

  // staging: per half-tile (128 rows x 64k = 16 KB) each thread does 2 gld16.
  // LDS linear dest (HW adds lane*16); global source pre-swizzled so that
  // LDS[r][s] = G[r][s ^ (r&7)], r&7 == (lane>>3)&7.
  const int inv_g = (w * 8 + (lane >> 3)) * ROWB + ((((lane & 7) ^ ((lane >> 3) & 7))) << 4);
  char* const lA = (char*)&sA[0][0][0] + w * 1024;
  char* const lB = (char*)&sB[0][0][0] + w * 1024;

#define STAGEH(srcbase, tilerow, ko, ldsroot, buf, h)                                  \
  do {                                                                                 \
    const char* g0_ = (srcbase) + (tilerow) + (size_t)(h) * (128 * (size_t)ROWB) +     \
                      (size_t)(ko) + inv_g;                                            \
    char* l0_ = (ldsroot) + (buf) * 32768 + (h) * 16384;                               \
    gld16(g0_, l0_);                                                                   \
    gld16(g0_ + (size_t)64 * ROWB, l0_ + 8192);                                        \
  } while (0)

  // per-tile operand-pair select
#define TSEL(X, sa_, sb_, ko_)                                                         \
  do {                                                                                 \
    int rg_ = ((X) >= 22) ? 2 : (((X) >= 11) ? 1 : 0);                                 \
    sa_ = (rg_ == 2) ? Al : Ah;                                                        \
    sb_ = (rg_ == 1) ? Bl : Bh;                                                        \
    ko_ = ((X) - rg_ * 11) * 128;                                                      \
  } while (0)

  // ds-read invariants. frag(row-blk f, kk): row = base + f*16 + (lane&15),
  // slot = (kk*4 + (lane>>4)) ^ (lane&7)  (row&7 == lane&7)
  const int rA0 = (wr * 128 + (lane & 15)) * 128;
  const int rB0 = (wc * 64 + (lane & 15)) * 128;
  const int x0 = (((lane >> 4)) ^ (lane & 7)) << 4;
  const int x1 = ((4 + (lane >> 4)) ^ (lane & 7)) << 4;

  f32x4 acc[8][4] = {};
  f16x8 ar[4][2], br[4][2];

  // ---- prologue: stage tile0 fully + tile1 {A0,A1,B0}; drain tile0 ----
  {
    const char *sa, *sb; int ko;
    TSEL(0, sa, sb, ko);
    STAGEH(sa, arow, ko, lA, 0, 0);
    STAGEH(sa, arow, ko, lA, 0, 1);
    STAGEH(sb, brow, ko, lB, 0, 0);
    STAGEH(sb, brow, ko, lB, 0, 1);
    TSEL(1, sa, sb, ko);
    STAGEH(sa, arow, ko, lA, 1, 0);
    STAGEH(sa, arow, ko, lA, 1, 1);
    STAGEH(sb, brow, ko, lB, 1, 0);
  }
  asm volatile("s_waitcnt vmcnt(6)" ::: "memory");
  __builtin_amdgcn_sched_barrier(0);
  __builtin_amdgcn_s_barrier();

#pragma unroll 1
  for (int T = 0; T < 33; ++T) {
    const int cur = T & 1;
    const char* sAc = (const char*)&sA[0][0][0] + cur * 32768;
    const char* sBc = (const char*)&sB[0][0][0] + cur * 32768;

    // ---- phase 0: read a0-3(kk0,kk1) + b0-1; issue B1(T+1) -> buf^1 ----
#pragma unroll
    for (int a = 0; a < 4; ++a) {
      ar[a][0] = *(const f16x8*)(sAc + rA0 + a * 2048 + x0);
      ar[a][1] = *(const f16x8*)(sAc + rA0 + a * 2048 + x1);
    }
#pragma unroll
    for (int b = 0; b < 2; ++b) {
      br[b][0] = *(const f16x8*)(sBc + rB0 + b * 2048 + x0);
      br[b][1] = *(const f16x8*)(sBc + rB0 + b * 2048 + x1);
    }
    if (T + 1 <= 32) {
      const char *sa, *sb; int ko;
      TSEL(T + 1, sa, sb, ko);
      STAGEH(sb, brow, ko, lB, cur ^ 1, 1);
    }
    __builtin_amdgcn_s_barrier();
    __builtin_amdgcn_s_setprio(1);
#pragma unroll
    for (int a = 0; a < 4; ++a)
#pragma unroll
      for (int b = 0; b < 2; ++b) {
        acc[a][b] = __builtin_amdgcn_mfma_f32_16x16x32_f16(ar[a][0], br[b][0], acc[a][b], 0, 0, 0);
        acc[a][b] = __builtin_amdgcn_mfma_f32_16x16x32_f16(ar[a][1], br[b][1], acc[a][b], 0, 0, 0);
      }
    __builtin_amdgcn_s_setprio(0);
    __builtin_amdgcn_s_barrier();

    // ---- phase 1: read b2-3; MFMA a0-3 x b2-3 ----
#pragma unroll
    for (int b = 2; b < 4; ++b) {
      br[b][0] = *(const f16x8*)(sBc + rB0 + b * 2048 + x0);
      br[b][1] = *(const f16x8*)(sBc + rB0 + b * 2048 + x1);
    }
    __builtin_amdgcn_s_setprio(1);
#pragma unroll
    for (int a = 0; a < 4; ++a)
#pragma unroll
      for (int b = 2; b < 4; ++b) {
        acc[a][b] = __builtin_amdgcn_mfma_f32_16x16x32_f16(ar[a][0], br[b][0], acc[a][b], 0, 0, 0);
        acc[a][b] = __builtin_amdgcn_mfma_f32_16x16x32_f16(ar[a][1], br[b][1], acc[a][b], 0, 0, 0);
      }
    __builtin_amdgcn_s_setprio(0);
    __builtin_amdgcn_s_barrier();

    // ---- phase 2: read a4-7 (overwrite ar); MFMA a4-7 x b0-1 ----
#pragma unroll
    for (int a = 0; a < 4; ++a) {
      ar[a][0] = *(const f16x8*)(sAc + rA0 + (a + 4) * 2048 + x0);
      ar[a][1] = *(const f16x8*)(sAc + rA0 + (a + 4) * 2048 + x1);
    }
    __builtin_amdgcn_s_setprio(1);
#pragma unroll
    for (int a = 0; a < 4; ++a)
#pragma unroll
      for (int b = 0; b < 2; ++b) {
        acc[a + 4][b] = __builtin_amdgcn_mfma_f32_16x16x32_f16(ar[a][0], br[b][0], acc[a + 4][b], 0, 0, 0);
        acc[a + 4][b] = __builtin_amdgcn_mfma_f32_16x16x32_f16(ar[a][1], br[b][1], acc[a + 4][b], 0, 0, 0);
      }
    __builtin_amdgcn_s_setprio(0);
    __builtin_amdgcn_s_barrier();

    // ---- phase 3: issue A0,A1,B0(T+2) -> buf[cur] (all buf[cur] reads done);
    //      MFMA a4-7 x b2-3; counted-vmcnt gate ----
    if (T + 2 <= 32) {
      const char *sa, *sb; int ko;
      TSEL(T + 2, sa, sb, ko);
      STAGEH(sa, arow, ko, lA, cur, 0);
      STAGEH(sa, arow, ko, lA, cur, 1);
      STAGEH(sb, brow, ko, lB, cur, 0);
    }
    __builtin_amdgcn_s_setprio(1);
#pragma unroll
    for (int a = 0; a < 4; ++a)
#pragma unroll
      for (int b = 2; b < 4; ++b) {
        acc[a + 4][b] = __builtin_amdgcn_mfma_f32_16x16x32_f16(ar[a][0], br[b][0], acc[a + 4][b], 0, 0, 0);
        acc[a + 4][b] = __builtin_amdgcn_mfma_f32_16x16x32_f16(ar[a][1], br[b][1], acc[a + 4][b], 0, 0, 0);
      }
    __builtin_amdgcn_s_setprio(0);
    if (T < 31) {
      asm volatile("s_waitcnt vmcnt(6)" ::: "memory");  // keep T+2's 3 halves in flight
    } else {
      asm volatile("s_waitcnt vmcnt(0)" ::: "memory");  // tail drain
    }
    __builtin_amdgcn_sched_barrier(0);
    __builtin_amdgcn_s_barrier();
  }

  // ---- fused top-1. C/D: col = lane&15, row = (lane>>4)*4 + reg ----
  const float scale = 1.0f / 65536.0f;  // undo 256^2
  const int R0 = bi * 256 + wr * 128;
  const int C0 = bj * 256 + wc * 64;

#pragma unroll
  for (int a = 0; a < 8; ++a) {
#pragma unroll
    for (int r = 0; r < 4; ++r) {
      float bv = acc[a][0][r];
      int bjx = C0 + (lane & 15);
#pragma unroll
      for (int b = 1; b < 4; ++b) {
        float v = acc[a][b][r];
        if (v > bv) { bv = v; bjx = C0 + b * 16 + (lane & 15); }
      }
      unsigned long long key = packkey(bv * scale, bjx);
#pragma unroll
      for (int off = 1; off < 16; off <<= 1) {
        unsigned long long o = __shfl_xor(key, off);
        if (o > key) key = o;
      }
      if ((lane & 15) == 0) {
        atomicMax(&rowbest[R0 + a * 16 + (lane >> 4) * 4 + r], key);
      }
    }
  }
#pragma unroll
  for (int b = 0; b < 4; ++b) {
    unsigned long long key = 0ull;
#pragma unroll
    for (int a = 0; a < 8; ++a)
#pragma unroll
      for (int r = 0; r < 4; ++r) {
        int i = R0 + a * 16 + (lane >> 4) * 4 + r;
        unsigned long long k2 = packkey(acc[a][b][r] * scale, i);
        if (k2 > key) key = k2;
      }
    unsigned long long o = __shfl_xor(key, 16); if (o > key) key = o;
    o = __shfl_xor(key, 32); if (o > key) key = o;
    if (lane < 16) atomicMax(&colbest[C0 + b * 16 + lane], key);
  }
#undef STAGEH
#undef TSEL
}

// ---- kernel 4: mutual-NN mask + output assembly (all f32) ----
__global__ void k_epilogue(const unsigned long long* __restrict__ rowbest,
                           const unsigned long long* __restrict__ colbest,
                           float* __restrict__ out) {
  int i = blockIdx.x * 256 + threadIdx.x;  // 0..8191
  unsigned long long rk = rowbest[i];
  int j = (int)(~(unsigned)rk);
  unsigned hb = (unsigned)(rk >> 32);
  hb ^= (hb >> 31) ? 0x80000000u : 0xFFFFFFFFu;
  float sim = __uint_as_float(hb);
  unsigned long long ck = colbest[j];
  int nn21 = (int)(~(unsigned)ck);
  bool m = (nn21 == i);
  out[2 * i]     = m ? (float)i : -1.0f;
  out[2 * i + 1] = m ? (float)j : -1.0f;
  out[2 * NPTS + i] = m ? sim : 0.0f;
  out[3 * NPTS + i] = m ? 1.0f : 0.0f;
}

extern "C" void kernel_launch(void* const* d_in, const int* in_sizes, int n_in,
                              void* d_out, int out_size, void* d_ws, size_t ws_size,
                              hipStream_t stream) {
  const float* A = (const float*)d_in[0];
  const float* B = (const float*)d_in[1];
  char* ws = (char*)d_ws;

  const size_t SPLIT = (size_t)NPTS * KD * 2;  // 11,534,336 B per array
  unsigned long long* rowbest = (unsigned long long*)(ws);
  unsigned long long* colbest = (unsigned long long*)(ws + 65536);
  float* invA = (float*)(ws + 131072);
  float* invB = (float*)(ws + 163840);
  f16* Ahi = (f16*)(ws + 196608);
  f16* Alo = (f16*)(ws + 196608 + SPLIT);
  f16* Bhi = (f16*)(ws + 196608 + 2 * SPLIT);
  f16* Blo = (f16*)(ws + 196608 + 3 * SPLIT);

  k_norm<<<512, 256, 0, stream>>>(A, B, invA, invB, rowbest /* + colbest contig */);
  dim3 g2(NPTS / 32, KD / 32, 2);
  k_split<<<g2, 256, 0, stream>>>(A, B, invA, invB, Ahi, Alo, Bhi, Blo);
  k_gemm_top1<<<1024, 512, 0, stream>>>(Ahi, Alo, Bhi, Blo, rowbest, colbest);
  k_epilogue<<<NPTS / 256, 256, 0, stream>>>(rowbest, colbest, (float*)d_out);
}

// Round 5
// 428.273 us; speedup vs baseline: 1.1112x; 1.1112x over previous
//
#include <hip/hip_runtime.h>
#include <stdint.h>
#include <math.h>

typedef _Float16 f16;
typedef _Float16 f16x8 __attribute__((ext_vector_type(8)));
typedef float f32x4 __attribute__((ext_vector_type(4)));

#define KD 704
#define NPTS 8192

typedef const unsigned __attribute__((address_space(1)))* gas_ptr;
typedef unsigned __attribute__((address_space(3)))* las_ptr;

__device__ __forceinline__ void gld16(const void* g, void* l) {
  __builtin_amdgcn_global_load_lds((gas_ptr)g, (las_ptr)l, 16, 0, 0);
}

__device__ __forceinline__ unsigned long long packkey(float v, int idx) {
  unsigned b = __float_as_uint(v);
  b ^= ((unsigned)((int)b >> 31)) | 0x80000000u;  // monotone float->uint
  return ((unsigned long long)b << 32) | (unsigned)(~idx);  // ~idx: ties -> smaller idx
}

// ---- kernel 1: column norms (x256 fold) + zero the 16K atomic slots ----
// (round-4 version: verified, part of the 46 us small-kernel total)
__global__ void k_norm(const float* __restrict__ A, const float* __restrict__ B,
                       float* __restrict__ invA, float* __restrict__ invB,
                       unsigned long long* __restrict__ slots) {
  __shared__ float p[256];
  const int blk = blockIdx.x;  // 0..511
  const int mat = blk >> 8;
  const float* M = mat ? B : A;
  float* inv = mat ? invB : invA;
  const int cbase = (blk & 255) << 5;
  const int c = cbase + (threadIdx.x & 31);
  const int s = threadIdx.x >> 5;  // 0..7
  float ss = 0.f;
  for (int d = s; d < KD; d += 8) {
    float x = M[(size_t)d * NPTS + c];
    ss = fmaf(x, x, ss);
  }
  p[threadIdx.x] = ss;
  if (blk < 64) slots[blk * 256 + threadIdx.x] = 0ull;  // rowbest+colbest (128 KB)
  __syncthreads();
  if (threadIdx.x < 32) {
    float t = 0.f;
    #pragma unroll
    for (int k = 0; k < 8; ++k) t += p[k * 32 + threadIdx.x];
    inv[cbase + threadIdx.x] = 256.0f / sqrtf(t);
  }
}

// ---- kernel 2: transpose (D,N)->(N,D), normalize, fp16 hi/lo split ----
// (round-4 version: verified)
__global__ void k_split(const float* __restrict__ A, const float* __restrict__ B,
                        const float* __restrict__ invA, const float* __restrict__ invB,
                        f16* __restrict__ Ahi, f16* __restrict__ Alo,
                        f16* __restrict__ Bhi, f16* __restrict__ Blo) {
  __shared__ float t[32][33];
  const int z = blockIdx.z;
  const float* M   = z ? B    : A;
  const float* inv = z ? invB : invA;
  f16* Hi = z ? Bhi : Ahi;
  f16* Lo = z ? Blo : Alo;
  const int c0 = blockIdx.x * 32, d0 = blockIdx.y * 32;
  const int tx = threadIdx.x & 31, ty = threadIdx.x >> 5;
  #pragma unroll
  for (int s = 0; s < 4; ++s)
    t[ty + s * 8][tx] = M[(size_t)(d0 + ty + s * 8) * NPTS + (c0 + tx)];
  __syncthreads();
  const int tx16 = threadIdx.x & 15, ty16 = threadIdx.x >> 4;  // 16x16
  #pragma unroll
  for (int s2 = 0; s2 < 2; ++s2) {
    const int i = c0 + ty16 + s2 * 16;
    const float iv = inv[i];
    const float v0 = t[tx16 * 2][ty16 + s2 * 16] * iv;
    const float v1 = t[tx16 * 2 + 1][ty16 + s2 * 16] * iv;
    const f16 h0 = (f16)v0, h1 = (f16)v1;
    const f16 l0 = (f16)(v0 - (float)h0), l1 = (f16)(v1 - (float)h1);
    const size_t o = (size_t)i * KD + d0 + tx16 * 2;
    Hi[o] = h0; Hi[o + 1] = h1;
    Lo[o] = l0; Lo[o + 1] = l1;
  }
}

// ---- kernel 3: 128x128-tile GEMM (f16 hi/lo, 3 products) + fused top-1 atomics ----
// (round-3 version VERBATIM: verified 310 us, 915 TF, absmax 0.0)
__global__ __launch_bounds__(256, 2)
void k_gemm_top1(const f16* __restrict__ Ahi, const f16* __restrict__ Alo,
                 const f16* __restrict__ Bhi, const f16* __restrict__ Blo,
                 unsigned long long* rowbest, unsigned long long* colbest) {
  // LDS tiles: [128 rows][64 k] f16 = 128B rows; XOR-8 swizzle on 16B slots.
  __shared__ f16 sAh[128 * 64];
  __shared__ f16 sAl[128 * 64];
  __shared__ f16 sBh[128 * 64];
  __shared__ f16 sBl[128 * 64];

  const int tid = threadIdx.x, lane = tid & 63, wave = tid >> 6;
  const int bj = blockIdx.x & 63, bi = blockIdx.x >> 6;
  const int wr = wave >> 1, wc = wave & 1;

  f32x4 acc[4][4] = {};

  // staging: wave w stages rows [w*32, w*32+32) of each tile; 4 instrs/tile.
  // LDS dest is linear (base + lane*16); global source is pre-swizzled:
  // data for (row, col-slot c) lands at LDS slot c ^ (row&7).
  const int srow = wave * 32 + (lane >> 3);        // q adds 8 -> (srow+q*8)&7 == srow&7
  const int cs   = ((lane & 7) ^ (srow & 7)) * 16; // swizzled source slot, bytes
  const size_t rowbytes = (size_t)KD * 2;          // 1408
  const char* pAh = (const char*)Ahi + (size_t)(bi * 128 + srow) * rowbytes + cs;
  const char* pAl = (const char*)Alo + (size_t)(bi * 128 + srow) * rowbytes + cs;
  const char* pBh = (const char*)Bhi + (size_t)(bj * 128 + srow) * rowbytes + cs;
  const char* pBl = (const char*)Blo + (size_t)(bj * 128 + srow) * rowbytes + cs;
  const unsigned lbase = wave * 4096;  // bytes; + q*1024; HW adds lane*16

  for (int ks = 0; ks < 11; ++ks) {
    const size_t kb = (size_t)ks * 128;  // k0 * 2 bytes
    #pragma unroll
    for (int q = 0; q < 4; ++q) {
      size_t go = kb + (size_t)q * 8 * rowbytes;
      unsigned lo_ = lbase + q * 1024;
      gld16(pAh + go, (char*)sAh + lo_);
      gld16(pAl + go, (char*)sAl + lo_);
      gld16(pBh + go, (char*)sBh + lo_);
      gld16(pBl + go, (char*)sBl + lo_);
    }
    __syncthreads();  // drains vmcnt before barrier (compiler-inserted)

    #pragma unroll
    for (int kk = 0; kk < 2; ++kk) {
      f16x8 ah[4], al[4], bh[4], bl[4];
      const int sa = ((kk * 4 + (lane >> 4)) ^ (lane & 7)) * 16;  // swizzled read slot
      #pragma unroll
      for (int a = 0; a < 4; ++a) {
        int row = wr * 64 + a * 16 + (lane & 15);
        ah[a] = *(const f16x8*)((const char*)sAh + row * 128 + sa);
        al[a] = *(const f16x8*)((const char*)sAl + row * 128 + sa);
      }
      #pragma unroll
      for (int b = 0; b < 4; ++b) {
        int row = wc * 64 + b * 16 + (lane & 15);
        bh[b] = *(const f16x8*)((const char*)sBh + row * 128 + sa);
        bl[b] = *(const f16x8*)((const char*)sBl + row * 128 + sa);
      }
      #pragma unroll
      for (int a = 0; a < 4; ++a)
        #pragma unroll
        for (int b = 0; b < 4; ++b) {
          acc[a][b] = __builtin_amdgcn_mfma_f32_16x16x32_f16(ah[a], bh[b], acc[a][b], 0, 0, 0);
          acc[a][b] = __builtin_amdgcn_mfma_f32_16x16x32_f16(ah[a], bl[b], acc[a][b], 0, 0, 0);
          acc[a][b] = __builtin_amdgcn_mfma_f32_16x16x32_f16(al[a], bh[b], acc[a][b], 0, 0, 0);
        }
    }
    __syncthreads();
  }

  // ---- fused top-1 reduction. C/D layout: col = lane&15, row = (lane>>4)*4 + reg ----
  const float scale = 1.0f / 65536.0f;  // undo S^2
  const int R0 = bi * 128 + wr * 64;
  const int C0 = bj * 128 + wc * 64;

  // rows: each 16-lane group (lane>>4) holds 4 rows (reg) x 4 (a); cols across lane&15 and b
  #pragma unroll
  for (int a = 0; a < 4; ++a) {
    #pragma unroll
    for (int r = 0; r < 4; ++r) {
      float bv = acc[a][0][r];
      int bjx = C0 + (lane & 15);
      #pragma unroll
      for (int b = 1; b < 4; ++b) {
        float v = acc[a][b][r];
        if (v > bv) { bv = v; bjx = C0 + b * 16 + (lane & 15); }
      }
      unsigned long long key = packkey(bv * scale, bjx);
      #pragma unroll
      for (int off = 1; off < 16; off <<= 1) {
        unsigned long long o = __shfl_xor(key, off);
        if (o > key) key = o;
      }
      if ((lane & 15) == 0) {
        int row = R0 + a * 16 + (lane >> 4) * 4 + r;
        atomicMax(&rowbest[row], key);
      }
    }
  }
  // cols: col = C0 + b*16 + (lane&15); rows spread over (lane>>4) groups and regs
  #pragma unroll
  for (int b = 0; b < 4; ++b) {
    unsigned long long key = 0ull;
    #pragma unroll
    for (int a = 0; a < 4; ++a)
      #pragma unroll
      for (int r = 0; r < 4; ++r) {
        int i = R0 + a * 16 + (lane >> 4) * 4 + r;
        unsigned long long k2 = packkey(acc[a][b][r] * scale, i);
        if (k2 > key) key = k2;
      }
    unsigned long long o = __shfl_xor(key, 16); if (o > key) key = o;
    o = __shfl_xor(key, 32); if (o > key) key = o;
    if (lane < 16) atomicMax(&colbest[C0 + b * 16 + lane], key);
  }
}

// ---- kernel 4: mutual-NN mask + output assembly (all f32) ----
__global__ void k_epilogue(const unsigned long long* __restrict__ rowbest,
                           const unsigned long long* __restrict__ colbest,
                           float* __restrict__ out) {
  int i = blockIdx.x * 256 + threadIdx.x;  // 0..8191
  unsigned long long rk = rowbest[i];
  int j = (int)(~(unsigned)rk);
  unsigned hb = (unsigned)(rk >> 32);
  hb ^= (hb >> 31) ? 0x80000000u : 0xFFFFFFFFu;
  float sim = __uint_as_float(hb);
  unsigned long long ck = colbest[j];
  int nn21 = (int)(~(unsigned)ck);
  bool m = (nn21 == i);
  out[2 * i]     = m ? (float)i : -1.0f;
  out[2 * i + 1] = m ? (float)j : -1.0f;
  out[2 * NPTS + i] = m ? sim : 0.0f;
  out[3 * NPTS + i] = m ? 1.0f : 0.0f;
}

extern "C" void kernel_launch(void* const* d_in, const int* in_sizes, int n_in,
                              void* d_out, int out_size, void* d_ws, size_t ws_size,
                              hipStream_t stream) {
  const float* A = (const float*)d_in[0];
  const float* B = (const float*)d_in[1];
  char* ws = (char*)d_ws;

  const size_t SPLIT = (size_t)NPTS * KD * 2;  // 11,534,336 B per array
  unsigned long long* rowbest = (unsigned long long*)(ws);
  unsigned long long* colbest = (unsigned long long*)(ws + 65536);
  float* invA = (float*)(ws + 131072);
  float* invB = (float*)(ws + 163840);
  f16* Ahi = (f16*)(ws + 196608);
  f16* Alo = (f16*)(ws + 196608 + SPLIT);
  f16* Bhi = (f16*)(ws + 196608 + 2 * SPLIT);
  f16* Blo = (f16*)(ws + 196608 + 3 * SPLIT);

  k_norm<<<512, 256, 0, stream>>>(A, B, invA, invB, rowbest /* + colbest contig */);
  dim3 g2(NPTS / 32, KD / 32, 2);
  k_split<<<g2, 256, 0, stream>>>(A, B, invA, invB, Ahi, Alo, Bhi, Blo);
  k_gemm_top1<<<4096, 256, 0, stream>>>(Ahi, Alo, Bhi, Blo, rowbest, colbest);
  k_epilogue<<<NPTS / 256, 256, 0, stream>>>(rowbest, colbest, (float*)d_out);
}